// Round 13
// baseline (142.166 us; speedup 1.0000x reference)
//
#include <hip/hip_runtime.h>
#include <hip/hip_bf16.h>

#define T_TOT 2304
#define DDIM  1024
#define NH    16
#define DK    64
#define SLEN  128
#define SEQ   2048

typedef __bf16 bf16x8 __attribute__((ext_vector_type(8)));
typedef __bf16 bf16x4 __attribute__((ext_vector_type(4)));
typedef float  f32x4  __attribute__((ext_vector_type(4)));

__device__ __forceinline__ void async_copy16(const void* gsrc, void* ldst) {
  __builtin_amdgcn_global_load_lds(
      (const __attribute__((address_space(1))) void*)gsrc,
      (__attribute__((address_space(3))) void*)ldst, 16, 0, 0);
}

// ---------------- convert: x -> bf16 (vectorized); W[h][d][n] -> Wt[m][h][n][d] via LDS transpose
__global__ __launch_bounds__(256) void convert_kernel(
    const float* __restrict__ x,
    const float* __restrict__ Wq, const float* __restrict__ Wk,
    const float* __restrict__ Wv, const float* __restrict__ Wqs,
    const float* __restrict__ Wks, const float* __restrict__ Wvs,
    __bf16* __restrict__ xb, __bf16* __restrict__ Wt) {
  const int b = blockIdx.x;
  const int tid = threadIdx.x;
  if (b < 576) {
    const float4* xin = (const float4*)x;
#pragma unroll
    for (int it = 0; it < 4; ++it) {
      int idx4 = b * 1024 + it * 256 + tid;
      float4 v = xin[idx4];
      bf16x4 o;
      o[0] = (__bf16)v.x; o[1] = (__bf16)v.y; o[2] = (__bf16)v.z; o[3] = (__bf16)v.w;
      *(bf16x4*)(xb + (size_t)idx4 * 4) = o;
    }
    return;
  }
  __shared__ float tile[64 * 65];
  const int wb = b - 576;
  const int m  = wb >> 8;
  const int rem = wb & 255;
  const int h  = rem >> 4;
  const int dt = rem & 15;
  const int d0 = dt * 64;
  const float* Wsrc = (m == 0 ? Wq : m == 1 ? Wk : m == 2 ? Wv
                      : m == 3 ? Wqs : m == 4 ? Wks : Wvs) + (size_t)h * (DDIM * DK);
#pragma unroll
  for (int rr = 0; rr < 4; ++rr) {
    int drow = rr * 16 + (tid >> 4);
    int nc   = (tid & 15) * 4;
    float4 v = *(const float4*)(Wsrc + (size_t)(d0 + drow) * DK + nc);
    tile[(nc + 0) * 65 + drow] = v.x;
    tile[(nc + 1) * 65 + drow] = v.y;
    tile[(nc + 2) * 65 + drow] = v.z;
    tile[(nc + 3) * 65 + drow] = v.w;
  }
  __syncthreads();
  {
    int n  = tid >> 2;
    int rg = (tid & 3) * 16;
    __bf16* dst = Wt + (((size_t)(m * NH + h)) * DK + n) * DDIM + d0 + rg;
    bf16x8 o0, o1;
#pragma unroll
    for (int e = 0; e < 8; e++) o0[e] = (__bf16)tile[n * 65 + rg + e];
#pragma unroll
    for (int e = 0; e < 8; e++) o1[e] = (__bf16)tile[n * 65 + rg + 8 + e];
    *(bf16x8*)dst = o0;
    *(bf16x8*)(dst + 8) = o1;
  }
}

// ---------------- proj v3 (measured-best ~26us): 64x128 tiles, grid (8,36,3)=864 blocks.
__global__ __launch_bounds__(256) void proj_kernel(
    const __bf16* __restrict__ xb, const __bf16* __restrict__ Wt,
    const float* __restrict__ scal,
    __bf16* __restrict__ qkv, __bf16* __restrict__ vt) {
  const int ntile = blockIdx.x;   // 0..7
  const int rt    = blockIdx.y;   // 0..35 (64-row tiles)
  const int which = blockIdx.z;   // 0=q 1=k 2=v
  const int r0    = rt * 64;
  const int m     = (rt < 2 || rt >= 34) ? which + 3 : which;

  __shared__ __bf16 Xs[64 * 64];     // 8 KB
  __shared__ __bf16 Wsh[128 * 64];   // 16 KB

  const int tid  = threadIdx.x;
  const int wave = tid >> 6, lane = tid & 63;
  const int quad = lane >> 4, lc = lane & 15;
  const int wr   = wave >> 1, wc = wave & 1;
  const int h    = ntile * 2 + wc;

  const __bf16* Wbase = Wt + ((size_t)m * NH) * (DK * DDIM) + (size_t)(ntile * 128) * DDIM;

  const f32x4 fz = {0.f, 0.f, 0.f, 0.f};
  f32x4 acc[2][4];
#pragma unroll
  for (int i = 0; i < 2; i++)
#pragma unroll
    for (int j = 0; j < 4; j++) acc[i][j] = fz;

  for (int k0 = 0; k0 < DDIM; k0 += 64) {
#pragma unroll
    for (int it = 0; it < 2; ++it) {
      int L = it * 256 + tid;
      int row = L >> 3, c = (L & 7) ^ (row & 7);
      async_copy16(xb + (size_t)(r0 + row) * DDIM + k0 + c * 8,
                   (char*)Xs + (size_t)(it * 256 + wave * 64) * 16);
    }
#pragma unroll
    for (int it = 0; it < 4; ++it) {
      int L = it * 256 + tid;
      int row = L >> 3, c = (L & 7) ^ (row & 7);
      async_copy16(Wbase + (size_t)row * DDIM + k0 + c * 8,
                   (char*)Wsh + (size_t)(it * 256 + wave * 64) * 16);
    }
    __syncthreads();
#pragma unroll
    for (int kk = 0; kk < 2; kk++) {
      bf16x8 afr[2], bfr[4];
#pragma unroll
      for (int i = 0; i < 2; i++) {
        int row = wr * 32 + i * 16 + lc;
        int ch  = (kk * 4 + quad) ^ (row & 7);
        afr[i] = *(const bf16x8*)(Xs + (row * 8 + ch) * 8);
      }
#pragma unroll
      for (int j = 0; j < 4; j++) {
        int row = wc * 64 + j * 16 + lc;
        int ch  = (kk * 4 + quad) ^ (row & 7);
        bfr[j] = *(const bf16x8*)(Wsh + (row * 8 + ch) * 8);
      }
#pragma unroll
      for (int i = 0; i < 2; i++)
#pragma unroll
        for (int j = 0; j < 4; j++)
          acc[i][j] = __builtin_amdgcn_mfma_f32_16x16x32_bf16(afr[i], bfr[j], acc[i][j], 0, 0, 0);
    }
    __syncthreads();
  }

  const float qscale = (which == 0) ? scal[h] * 1.44269504088896f : 1.0f;
  float inv4[2][4];
#pragma unroll
  for (int i = 0; i < 2; i++) {
#pragma unroll
    for (int r = 0; r < 4; r++) {
      float s = 0.f;
#pragma unroll
      for (int j = 0; j < 4; j++) { float v = acc[i][j][r]; s += v * v; }
#pragma unroll
      for (int off = 1; off < 16; off <<= 1) s += __shfl_xor(s, off, 64);
      inv4[i][r] = qscale / fmaxf(sqrtf(s), 1e-12f);
    }
  }
  if (which == 2) {
    __bf16* vtp = vt + (size_t)h * (DK * T_TOT);
#pragma unroll
    for (int i = 0; i < 2; i++) {
      int rowbase = r0 + wr * 32 + i * 16 + quad * 4;
#pragma unroll
      for (int j = 0; j < 4; j++) {
        bf16x4 o;
#pragma unroll
        for (int r = 0; r < 4; r++) o[r] = (__bf16)(acc[i][j][r] * inv4[i][r]);
        *(bf16x4*)(vtp + (size_t)(j * 16 + lc) * T_TOT + rowbase) = o;
      }
    }
  } else {
    __bf16* outp = qkv + ((size_t)(which * NH + h)) * ((size_t)T_TOT * DK);
#pragma unroll
    for (int i = 0; i < 2; i++)
#pragma unroll
      for (int r = 0; r < 4; r++) {
        int row = r0 + wr * 32 + i * 16 + quad * 4 + r;
#pragma unroll
        for (int j = 0; j < 4; j++)
          outp[(size_t)row * DK + j * 16 + lc] = (__bf16)(acc[i][j][r] * inv4[i][r]);
      }
  }
}

// ---------------- flash attention v12 + T5 setprio (r10 best, 140.8us):
// wave-local q-slices, 2-way kv split, wave-private LDS P, no fences/atomics.
__global__ __launch_bounds__(256, 3) void attn_kernel(
    const __bf16* __restrict__ qkv, const __bf16* __restrict__ vt,
    float* __restrict__ Opart, float* __restrict__ Lpart) {
  const int b    = blockIdx.x;          // 0..1151
  const int h    = b & 15;
  const int rest = b >> 4;              // 0..71
  const int qg   = 35 - (rest >> 1);    // big work first
  const int si   = rest & 1;            // kv split index
  const int q0b  = qg * 64;
  const int tid  = threadIdx.x;
  const int wave = tid >> 6, lane = tid & 63;
  const int quad = lane >> 4, lc = lane & 15;

  const __bf16* qp = qkv + ((size_t)h) * ((size_t)T_TOT * DK);
  const __bf16* kp = qkv + ((size_t)(NH + h)) * ((size_t)T_TOT * DK);
  const __bf16* vp = vt + (size_t)h * (DK * T_TOT);

  // 40 KB shared: Ks[2][64*64] | Vs[2][64*64] | P[4 waves][16*64]
  __shared__ __align__(16) char smem[40960];
  __bf16* Ks = (__bf16*)smem;
  __bf16* Vs = (__bf16*)(smem + 16384);
  __bf16* Pw = (__bf16*)(smem + 32768) + wave * 1024;  // own [16 q][64 kv] slice

  // Q B-frags for this wave's 16 q rows: B[k=d][n=q=lc]
  bf16x8 qf[2];
#pragma unroll
  for (int kk = 0; kk < 2; kk++)
    qf[kk] = *(const bf16x8*)(qp + (size_t)(q0b + wave * 16 + lc) * DK + kk * 32 + quad * 8);

  const f32x4 fz = {0.f, 0.f, 0.f, 0.f};
  f32x4 acc[4];                          // O^T: d-tile dt -> rows quad*4+r, col q=lc
#pragma unroll
  for (int dt = 0; dt < 4; dt++) acc[dt] = fz;
  float lp = 0.f;

  // kv range for this split
  const int jsAll = (q0b >= SLEN + SEQ) ? 2 : 0;
  const int n     = qg - jsAll + 1;
  const int half  = (n + 1) >> 1;
  const int j0    = jsAll + (si ? half : 0);
  const int j1    = si ? qg : (jsAll + half - 1);

  auto stage = [&](int j, int bufi) {
    const __bf16* kT = kp + (size_t)j * 64 * DK;
    __bf16* Kd = Ks + bufi * 4096;
    __bf16* Vd = Vs + bufi * 4096;
#pragma unroll
    for (int it = 0; it < 2; ++it) {
      int L = it * 256 + tid;
      int row = L >> 3, c = (L & 7) ^ (row & 7);
      async_copy16(kT + (size_t)row * DK + c * 8,
                   (char*)Kd + (size_t)(it * 256 + wave * 64) * 16);
    }
#pragma unroll
    for (int it = 0; it < 2; ++it) {
      int L = it * 256 + tid;
      int d = L >> 3, c = (L & 7) ^ (d & 7);
      async_copy16(vp + (size_t)d * T_TOT + j * 64 + c * 8,
                   (char*)Vd + (size_t)(it * 256 + wave * 64) * 16);
    }
  };

  int cur = 0;
  if (j0 <= j1) stage(j0, 0);

  for (int j = j0; j <= j1; ++j) {
    __syncthreads();                    // tile j staged; buffers safe to swap
    if (j < j1) stage(j + 1, cur ^ 1);

    const __bf16* Kc = Ks + cur * 4096;
    const __bf16* Vc = Vs + cur * 4096;

    // S^T[64 kv][16 q]: A = K-frag (m=kv), B = qf (n=q)
    f32x4 s[4];
    __builtin_amdgcn_s_setprio(1);
#pragma unroll
    for (int kvt = 0; kvt < 4; kvt++) {
      int row = kvt * 16 + lc;
      bf16x8 a0 = *(const bf16x8*)(Kc + (row * 8 + (quad ^ (lc & 7))) * 8);
      bf16x8 a1 = *(const bf16x8*)(Kc + (row * 8 + ((4 + quad) ^ (lc & 7))) * 8);
      f32x4 t = __builtin_amdgcn_mfma_f32_16x16x32_bf16(a0, qf[0], fz, 0, 0, 0);
      s[kvt]  = __builtin_amdgcn_mfma_f32_16x16x32_bf16(a1, qf[1], t, 0, 0, 0);
    }
    __builtin_amdgcn_s_setprio(0);

    const bool diag = (j == qg);
    // fixed-shift softmax + pack into wave-private swizzled P slice
#pragma unroll
    for (int kvt = 0; kvt < 4; kvt++) {
      if (diag) {
#pragma unroll
        for (int r = 0; r < 4; r++)
          if ((kvt * 16 + quad * 4 + r) > (wave * 16 + lc)) s[kvt][r] = -__builtin_inff();
      }
      bf16x4 pb;
#pragma unroll
      for (int r = 0; r < 4; r++) {
        float pe = exp2f(s[kvt][r]);
        lp += pe;
        pb[r] = (__bf16)pe;
      }
      int c = (kvt * 4 + quad) ^ ((lc & 7) << 1);   // 8B-chunk XOR swizzle
      *(bf16x4*)(Pw + lc * 64 + c * 4) = pb;
    }

    // PV: O^T[64d][16q] += V^T P^T  (wave-private P, in-order LDS: no barrier)
    bf16x8 pB[2];
#pragma unroll
    for (int kk = 0; kk < 2; kk++)
      pB[kk] = *(const bf16x8*)(Pw + lc * 64 + ((kk * 8 + quad * 2) ^ ((lc & 7) << 1)) * 4);
    __builtin_amdgcn_s_setprio(1);
#pragma unroll
    for (int dt = 0; dt < 4; dt++) {
      int row = dt * 16 + lc;
#pragma unroll
      for (int kk = 0; kk < 2; kk++) {
        bf16x8 vA = *(const bf16x8*)(Vc + (row * 8 + ((kk * 4 + quad) ^ (lc & 7))) * 8);
        acc[dt] = __builtin_amdgcn_mfma_f32_16x16x32_bf16(vA, pB[kk], acc[dt], 0, 0, 0);
      }
    }
    __builtin_amdgcn_s_setprio(0);
    cur ^= 1;
  }

  // l reduce: quads hold disjoint kv partials for q=lc
  lp += __shfl_xor(lp, 16, 64);
  lp += __shfl_xor(lp, 32, 64);
  if (lane < 16) Lpart[(size_t)b * 64 + wave * 16 + lane] = lp;

  // O^T[d][q] -> Opart[q][d] via per-wave LDS transpose (reuse smem; pad 68)
  __syncthreads();
  float* Ot = (float*)smem + wave * (16 * 68);
#pragma unroll
  for (int dt = 0; dt < 4; dt++)
#pragma unroll
    for (int r = 0; r < 4; r++)
      Ot[lc * 68 + dt * 16 + quad * 4 + r] = acc[dt][r];

  float* Ob = Opart + (size_t)b * 4096;
  const int q2 = lane >> 2, dsg = (lane & 3) * 16;
#pragma unroll
  for (int g = 0; g < 4; g++) {
    f32x4 v = *(const f32x4*)(&Ot[q2 * 68 + dsg + g * 4]);
    *(f32x4*)(&Ob[(size_t)(wave * 16 + q2) * 64 + dsg + g * 4]) = v;
  }
}

// ---------------- combine: out = (O0 + O1) / (l0 + l1)
__global__ __launch_bounds__(256) void combine_kernel(
    const float* __restrict__ Opart, const float* __restrict__ Lpart,
    float* __restrict__ out) {
  const int b  = blockIdx.x;            // 0..575
  const int h  = b & 15;
  const int qg = b >> 4;
  const int b0 = (((35 - qg) * 2) << 4) | h;
  const int b1 = b0 + 16;
  const int tid = threadIdx.x;

  __shared__ float invl[64];
  if (tid < 64)
    invl[tid] = 1.0f / (Lpart[(size_t)b0 * 64 + tid] + Lpart[(size_t)b1 * 64 + tid]);
  __syncthreads();

  const float* O0 = Opart + (size_t)b0 * 4096;
  const float* O1 = Opart + (size_t)b1 * 4096;
  float* op = out + ((size_t)h * T_TOT + qg * 64) * DK;
#pragma unroll
  for (int it = 0; it < 4; ++it) {
    int i4 = it * 256 + tid;            // vec4 index, 0..1023
    f32x4 a = *(const f32x4*)(&O0[i4 * 4]);
    f32x4 c = *(const f32x4*)(&O1[i4 * 4]);
    float iv = invl[i4 >> 4];
    f32x4 o;
#pragma unroll
    for (int r = 0; r < 4; r++) o[r] = (a[r] + c[r]) * iv;
    *(f32x4*)(&op[i4 * 4]) = o;
  }
}

extern "C" void kernel_launch(void* const* d_in, const int* in_sizes, int n_in,
                              void* d_out, int out_size, void* d_ws, size_t ws_size,
                              hipStream_t stream) {
  const float* x    = (const float*)d_in[0];
  const float* Wq   = (const float*)d_in[1];
  const float* Wk   = (const float*)d_in[2];
  const float* Wv   = (const float*)d_in[3];
  const float* Wqs  = (const float*)d_in[4];
  const float* Wks  = (const float*)d_in[5];
  const float* Wvs  = (const float*)d_in[6];
  const float* scal = (const float*)d_in[7];
  float* out = (float*)d_out;

  char* ws = (char*)d_ws;
  size_t off = 0;
  __bf16* xb    = (__bf16*)(ws + off); off += (size_t)T_TOT * DDIM * 2;
  __bf16* Wt    = (__bf16*)(ws + off); off += (size_t)6 * NH * DK * DDIM * 2;
  __bf16* qkv   = (__bf16*)(ws + off); off += (size_t)2 * NH * T_TOT * DK * 2;
  __bf16* vt    = (__bf16*)(ws + off); off += (size_t)NH * DK * T_TOT * 2;
  float*  Opart = (float*)(ws + off);  off += (size_t)1152 * 4096 * 4;
  float*  Lpart = (float*)(ws + off);

  convert_kernel<<<2112, 256, 0, stream>>>(x, Wq, Wk, Wv, Wqs, Wks, Wvs, xb, Wt);
  proj_kernel<<<dim3(8, 36, 3), 256, 0, stream>>>(xb, Wt, scal, qkv, vt);
  attn_kernel<<<dim3(1152), 256, 0, stream>>>(qkv, vt, Opart, Lpart);
  combine_kernel<<<dim3(576), 256, 0, stream>>>(Opart, Lpart, out);
}

// Round 14
// 140.691 us; speedup vs baseline: 1.0105x; 1.0105x over previous
//
#include <hip/hip_runtime.h>
#include <hip/hip_bf16.h>

#define T_TOT 2304
#define DDIM  1024
#define NH    16
#define DK    64
#define SLEN  128
#define SEQ   2048

typedef __bf16 bf16x8 __attribute__((ext_vector_type(8)));
typedef __bf16 bf16x4 __attribute__((ext_vector_type(4)));
typedef float  f32x4  __attribute__((ext_vector_type(4)));

__device__ __forceinline__ void async_copy16(const void* gsrc, void* ldst) {
  __builtin_amdgcn_global_load_lds(
      (const __attribute__((address_space(1))) void*)gsrc,
      (__attribute__((address_space(3))) void*)ldst, 16, 0, 0);
}

// ---------------- convert: x -> bf16 (vectorized); W[h][d][n] -> Wt[m][h][n][d] via LDS transpose
__global__ __launch_bounds__(256) void convert_kernel(
    const float* __restrict__ x,
    const float* __restrict__ Wq, const float* __restrict__ Wk,
    const float* __restrict__ Wv, const float* __restrict__ Wqs,
    const float* __restrict__ Wks, const float* __restrict__ Wvs,
    __bf16* __restrict__ xb, __bf16* __restrict__ Wt) {
  const int b = blockIdx.x;
  const int tid = threadIdx.x;
  if (b < 576) {
    const float4* xin = (const float4*)x;
#pragma unroll
    for (int it = 0; it < 4; ++it) {
      int idx4 = b * 1024 + it * 256 + tid;
      float4 v = xin[idx4];
      bf16x4 o;
      o[0] = (__bf16)v.x; o[1] = (__bf16)v.y; o[2] = (__bf16)v.z; o[3] = (__bf16)v.w;
      *(bf16x4*)(xb + (size_t)idx4 * 4) = o;
    }
    return;
  }
  __shared__ float tile[64 * 65];
  const int wb = b - 576;
  const int m  = wb >> 8;
  const int rem = wb & 255;
  const int h  = rem >> 4;
  const int dt = rem & 15;
  const int d0 = dt * 64;
  const float* Wsrc = (m == 0 ? Wq : m == 1 ? Wk : m == 2 ? Wv
                      : m == 3 ? Wqs : m == 4 ? Wks : Wvs) + (size_t)h * (DDIM * DK);
#pragma unroll
  for (int rr = 0; rr < 4; ++rr) {
    int drow = rr * 16 + (tid >> 4);
    int nc   = (tid & 15) * 4;
    float4 v = *(const float4*)(Wsrc + (size_t)(d0 + drow) * DK + nc);
    tile[(nc + 0) * 65 + drow] = v.x;
    tile[(nc + 1) * 65 + drow] = v.y;
    tile[(nc + 2) * 65 + drow] = v.z;
    tile[(nc + 3) * 65 + drow] = v.w;
  }
  __syncthreads();
  {
    int n  = tid >> 2;
    int rg = (tid & 3) * 16;
    __bf16* dst = Wt + (((size_t)(m * NH + h)) * DK + n) * DDIM + d0 + rg;
    bf16x8 o0, o1;
#pragma unroll
    for (int e = 0; e < 8; e++) o0[e] = (__bf16)tile[n * 65 + rg + e];
#pragma unroll
    for (int e = 0; e < 8; e++) o1[e] = (__bf16)tile[n * 65 + rg + 8 + e];
    *(bf16x8*)dst = o0;
    *(bf16x8*)(dst + 8) = o1;
  }
}

// ---------------- proj v3 (measured-best ~26us): 64x128 tiles, grid (8,36,3)=864 blocks.
__global__ __launch_bounds__(256) void proj_kernel(
    const __bf16* __restrict__ xb, const __bf16* __restrict__ Wt,
    const float* __restrict__ scal,
    __bf16* __restrict__ qkv, __bf16* __restrict__ vt) {
  const int ntile = blockIdx.x;   // 0..7
  const int rt    = blockIdx.y;   // 0..35 (64-row tiles)
  const int which = blockIdx.z;   // 0=q 1=k 2=v
  const int r0    = rt * 64;
  const int m     = (rt < 2 || rt >= 34) ? which + 3 : which;

  __shared__ __bf16 Xs[64 * 64];     // 8 KB
  __shared__ __bf16 Wsh[128 * 64];   // 16 KB

  const int tid  = threadIdx.x;
  const int wave = tid >> 6, lane = tid & 63;
  const int quad = lane >> 4, lc = lane & 15;
  const int wr   = wave >> 1, wc = wave & 1;
  const int h    = ntile * 2 + wc;

  const __bf16* Wbase = Wt + ((size_t)m * NH) * (DK * DDIM) + (size_t)(ntile * 128) * DDIM;

  const f32x4 fz = {0.f, 0.f, 0.f, 0.f};
  f32x4 acc[2][4];
#pragma unroll
  for (int i = 0; i < 2; i++)
#pragma unroll
    for (int j = 0; j < 4; j++) acc[i][j] = fz;

  for (int k0 = 0; k0 < DDIM; k0 += 64) {
#pragma unroll
    for (int it = 0; it < 2; ++it) {
      int L = it * 256 + tid;
      int row = L >> 3, c = (L & 7) ^ (row & 7);
      async_copy16(xb + (size_t)(r0 + row) * DDIM + k0 + c * 8,
                   (char*)Xs + (size_t)(it * 256 + wave * 64) * 16);
    }
#pragma unroll
    for (int it = 0; it < 4; ++it) {
      int L = it * 256 + tid;
      int row = L >> 3, c = (L & 7) ^ (row & 7);
      async_copy16(Wbase + (size_t)row * DDIM + k0 + c * 8,
                   (char*)Wsh + (size_t)(it * 256 + wave * 64) * 16);
    }
    __syncthreads();
#pragma unroll
    for (int kk = 0; kk < 2; kk++) {
      bf16x8 afr[2], bfr[4];
#pragma unroll
      for (int i = 0; i < 2; i++) {
        int row = wr * 32 + i * 16 + lc;
        int ch  = (kk * 4 + quad) ^ (row & 7);
        afr[i] = *(const bf16x8*)(Xs + (row * 8 + ch) * 8);
      }
#pragma unroll
      for (int j = 0; j < 4; j++) {
        int row = wc * 64 + j * 16 + lc;
        int ch  = (kk * 4 + quad) ^ (row & 7);
        bfr[j] = *(const bf16x8*)(Wsh + (row * 8 + ch) * 8);
      }
#pragma unroll
      for (int i = 0; i < 2; i++)
#pragma unroll
        for (int j = 0; j < 4; j++)
          acc[i][j] = __builtin_amdgcn_mfma_f32_16x16x32_bf16(afr[i], bfr[j], acc[i][j], 0, 0, 0);
    }
    __syncthreads();
  }

  const float qscale = (which == 0) ? scal[h] * 1.44269504088896f : 1.0f;
  float inv4[2][4];
#pragma unroll
  for (int i = 0; i < 2; i++) {
#pragma unroll
    for (int r = 0; r < 4; r++) {
      float s = 0.f;
#pragma unroll
      for (int j = 0; j < 4; j++) { float v = acc[i][j][r]; s += v * v; }
#pragma unroll
      for (int off = 1; off < 16; off <<= 1) s += __shfl_xor(s, off, 64);
      inv4[i][r] = qscale / fmaxf(sqrtf(s), 1e-12f);
    }
  }
  if (which == 2) {
    __bf16* vtp = vt + (size_t)h * (DK * T_TOT);
#pragma unroll
    for (int i = 0; i < 2; i++) {
      int rowbase = r0 + wr * 32 + i * 16 + quad * 4;
#pragma unroll
      for (int j = 0; j < 4; j++) {
        bf16x4 o;
#pragma unroll
        for (int r = 0; r < 4; r++) o[r] = (__bf16)(acc[i][j][r] * inv4[i][r]);
        *(bf16x4*)(vtp + (size_t)(j * 16 + lc) * T_TOT + rowbase) = o;
      }
    }
  } else {
    __bf16* outp = qkv + ((size_t)(which * NH + h)) * ((size_t)T_TOT * DK);
#pragma unroll
    for (int i = 0; i < 2; i++)
#pragma unroll
      for (int r = 0; r < 4; r++) {
        int row = r0 + wr * 32 + i * 16 + quad * 4 + r;
#pragma unroll
        for (int j = 0; j < 4; j++)
          outp[(size_t)row * DK + j * 16 + lc] = (__bf16)(acc[i][j][r] * inv4[i][r]);
      }
  }
}

// ---------------- flash attention v18: r10/r13 structure EXACTLY; only the Opart
// handoff is bf16 (halves attn partial-write + combine partial-read traffic).
// Sums and normalization remain f32.
__global__ __launch_bounds__(256, 3) void attn_kernel(
    const __bf16* __restrict__ qkv, const __bf16* __restrict__ vt,
    __bf16* __restrict__ Opart, float* __restrict__ Lpart) {
  const int b    = blockIdx.x;          // 0..1151
  const int h    = b & 15;
  const int rest = b >> 4;              // 0..71
  const int qg   = 35 - (rest >> 1);    // big work first
  const int si   = rest & 1;            // kv split index
  const int q0b  = qg * 64;
  const int tid  = threadIdx.x;
  const int wave = tid >> 6, lane = tid & 63;
  const int quad = lane >> 4, lc = lane & 15;

  const __bf16* qp = qkv + ((size_t)h) * ((size_t)T_TOT * DK);
  const __bf16* kp = qkv + ((size_t)(NH + h)) * ((size_t)T_TOT * DK);
  const __bf16* vp = vt + (size_t)h * (DK * T_TOT);

  // 40 KB shared: Ks[2][64*64] | Vs[2][64*64] | P[4 waves][16*64]
  __shared__ __align__(16) char smem[40960];
  __bf16* Ks = (__bf16*)smem;
  __bf16* Vs = (__bf16*)(smem + 16384);
  __bf16* Pw = (__bf16*)(smem + 32768) + wave * 1024;  // own [16 q][64 kv] slice

  // Q B-frags for this wave's 16 q rows: B[k=d][n=q=lc]
  bf16x8 qf[2];
#pragma unroll
  for (int kk = 0; kk < 2; kk++)
    qf[kk] = *(const bf16x8*)(qp + (size_t)(q0b + wave * 16 + lc) * DK + kk * 32 + quad * 8);

  const f32x4 fz = {0.f, 0.f, 0.f, 0.f};
  f32x4 acc[4];                          // O^T: d-tile dt -> rows quad*4+r, col q=lc
#pragma unroll
  for (int dt = 0; dt < 4; dt++) acc[dt] = fz;
  float lp = 0.f;

  // kv range for this split
  const int jsAll = (q0b >= SLEN + SEQ) ? 2 : 0;
  const int n     = qg - jsAll + 1;
  const int half  = (n + 1) >> 1;
  const int j0    = jsAll + (si ? half : 0);
  const int j1    = si ? qg : (jsAll + half - 1);

  auto stage = [&](int j, int bufi) {
    const __bf16* kT = kp + (size_t)j * 64 * DK;
    __bf16* Kd = Ks + bufi * 4096;
    __bf16* Vd = Vs + bufi * 4096;
#pragma unroll
    for (int it = 0; it < 2; ++it) {
      int L = it * 256 + tid;
      int row = L >> 3, c = (L & 7) ^ (row & 7);
      async_copy16(kT + (size_t)row * DK + c * 8,
                   (char*)Kd + (size_t)(it * 256 + wave * 64) * 16);
    }
#pragma unroll
    for (int it = 0; it < 2; ++it) {
      int L = it * 256 + tid;
      int d = L >> 3, c = (L & 7) ^ (d & 7);
      async_copy16(vp + (size_t)d * T_TOT + j * 64 + c * 8,
                   (char*)Vd + (size_t)(it * 256 + wave * 64) * 16);
    }
  };

  int cur = 0;
  if (j0 <= j1) stage(j0, 0);

  for (int j = j0; j <= j1; ++j) {
    __syncthreads();                    // tile j staged; buffers safe to swap
    if (j < j1) stage(j + 1, cur ^ 1);

    const __bf16* Kc = Ks + cur * 4096;
    const __bf16* Vc = Vs + cur * 4096;

    // S^T[64 kv][16 q]: A = K-frag (m=kv), B = qf (n=q)
    f32x4 s[4];
    __builtin_amdgcn_s_setprio(1);
#pragma unroll
    for (int kvt = 0; kvt < 4; kvt++) {
      int row = kvt * 16 + lc;
      bf16x8 a0 = *(const bf16x8*)(Kc + (row * 8 + (quad ^ (lc & 7))) * 8);
      bf16x8 a1 = *(const bf16x8*)(Kc + (row * 8 + ((4 + quad) ^ (lc & 7))) * 8);
      f32x4 t = __builtin_amdgcn_mfma_f32_16x16x32_bf16(a0, qf[0], fz, 0, 0, 0);
      s[kvt]  = __builtin_amdgcn_mfma_f32_16x16x32_bf16(a1, qf[1], t, 0, 0, 0);
    }
    __builtin_amdgcn_s_setprio(0);

    const bool diag = (j == qg);
    // fixed-shift softmax + pack into wave-private swizzled P slice
#pragma unroll
    for (int kvt = 0; kvt < 4; kvt++) {
      if (diag) {
#pragma unroll
        for (int r = 0; r < 4; r++)
          if ((kvt * 16 + quad * 4 + r) > (wave * 16 + lc)) s[kvt][r] = -__builtin_inff();
      }
      bf16x4 pb;
#pragma unroll
      for (int r = 0; r < 4; r++) {
        float pe = exp2f(s[kvt][r]);
        lp += pe;
        pb[r] = (__bf16)pe;
      }
      int c = (kvt * 4 + quad) ^ ((lc & 7) << 1);   // 8B-chunk XOR swizzle
      *(bf16x4*)(Pw + lc * 64 + c * 4) = pb;
    }

    // PV: O^T[64d][16q] += V^T P^T  (wave-private P, in-order LDS: no barrier)
    bf16x8 pB[2];
#pragma unroll
    for (int kk = 0; kk < 2; kk++)
      pB[kk] = *(const bf16x8*)(Pw + lc * 64 + ((kk * 8 + quad * 2) ^ ((lc & 7) << 1)) * 4);
    __builtin_amdgcn_s_setprio(1);
#pragma unroll
    for (int dt = 0; dt < 4; dt++) {
      int row = dt * 16 + lc;
#pragma unroll
      for (int kk = 0; kk < 2; kk++) {
        bf16x8 vA = *(const bf16x8*)(Vc + (row * 8 + ((kk * 4 + quad) ^ (lc & 7))) * 8);
        acc[dt] = __builtin_amdgcn_mfma_f32_16x16x32_bf16(vA, pB[kk], acc[dt], 0, 0, 0);
      }
    }
    __builtin_amdgcn_s_setprio(0);
    cur ^= 1;
  }

  // l reduce: quads hold disjoint kv partials for q=lc
  lp += __shfl_xor(lp, 16, 64);
  lp += __shfl_xor(lp, 32, 64);
  if (lane < 16) Lpart[(size_t)b * 64 + wave * 16 + lane] = lp;

  // O^T[d][q] -> Opart[q][d] (bf16) via per-wave LDS transpose (reuse smem; pad 68)
  __syncthreads();
  float* Ot = (float*)smem + wave * (16 * 68);
#pragma unroll
  for (int dt = 0; dt < 4; dt++)
#pragma unroll
    for (int r = 0; r < 4; r++)
      Ot[lc * 68 + dt * 16 + quad * 4 + r] = acc[dt][r];

  __bf16* Ob = Opart + (size_t)b * 4096;
  const int q2 = lane >> 2, dsg = (lane & 3) * 16;
#pragma unroll
  for (int g = 0; g < 4; g++) {
    f32x4 v = *(const f32x4*)(&Ot[q2 * 68 + dsg + g * 4]);
    bf16x4 o;
#pragma unroll
    for (int r = 0; r < 4; r++) o[r] = (__bf16)v[r];
    *(bf16x4*)(&Ob[(size_t)(wave * 16 + q2) * 64 + dsg + g * 4]) = o;
  }
}

// ---------------- combine: out = (O0 + O1) / (l0 + l1), O partials in bf16
__global__ __launch_bounds__(256) void combine_kernel(
    const __bf16* __restrict__ Opart, const float* __restrict__ Lpart,
    float* __restrict__ out) {
  const int b  = blockIdx.x;            // 0..575
  const int h  = b & 15;
  const int qg = b >> 4;
  const int b0 = (((35 - qg) * 2) << 4) | h;
  const int b1 = b0 + 16;
  const int tid = threadIdx.x;

  __shared__ float invl[64];
  if (tid < 64)
    invl[tid] = 1.0f / (Lpart[(size_t)b0 * 64 + tid] + Lpart[(size_t)b1 * 64 + tid]);
  __syncthreads();

  const __bf16* O0 = Opart + (size_t)b0 * 4096;
  const __bf16* O1 = Opart + (size_t)b1 * 4096;
  float* op = out + ((size_t)h * T_TOT + qg * 64) * DK;
#pragma unroll
  for (int it = 0; it < 4; ++it) {
    int i4 = it * 256 + tid;            // vec4 index, 0..1023
    bf16x4 a = *(const bf16x4*)(&O0[(size_t)i4 * 4]);
    bf16x4 c = *(const bf16x4*)(&O1[(size_t)i4 * 4]);
    float iv = invl[i4 >> 4];
    f32x4 o;
#pragma unroll
    for (int r = 0; r < 4; r++) o[r] = ((float)a[r] + (float)c[r]) * iv;
    *(f32x4*)(&op[(size_t)i4 * 4]) = o;
  }
}

extern "C" void kernel_launch(void* const* d_in, const int* in_sizes, int n_in,
                              void* d_out, int out_size, void* d_ws, size_t ws_size,
                              hipStream_t stream) {
  const float* x    = (const float*)d_in[0];
  const float* Wq   = (const float*)d_in[1];
  const float* Wk   = (const float*)d_in[2];
  const float* Wv   = (const float*)d_in[3];
  const float* Wqs  = (const float*)d_in[4];
  const float* Wks  = (const float*)d_in[5];
  const float* Wvs  = (const float*)d_in[6];
  const float* scal = (const float*)d_in[7];
  float* out = (float*)d_out;

  char* ws = (char*)d_ws;
  size_t off = 0;
  __bf16* xb    = (__bf16*)(ws + off); off += (size_t)T_TOT * DDIM * 2;
  __bf16* Wt    = (__bf16*)(ws + off); off += (size_t)6 * NH * DK * DDIM * 2;
  __bf16* qkv   = (__bf16*)(ws + off); off += (size_t)2 * NH * T_TOT * DK * 2;
  __bf16* vt    = (__bf16*)(ws + off); off += (size_t)NH * DK * T_TOT * 2;
  __bf16* Opart = (__bf16*)(ws + off); off += (size_t)1152 * 4096 * 2;
  float*  Lpart = (float*)(ws + off);

  convert_kernel<<<2112, 256, 0, stream>>>(x, Wq, Wk, Wv, Wqs, Wks, Wvs, xb, Wt);
  proj_kernel<<<dim3(8, 36, 3), 256, 0, stream>>>(xb, Wt, scal, qkv, vt);
  attn_kernel<<<dim3(1152), 256, 0, stream>>>(qkv, vt, Opart, Lpart);
  combine_kernel<<<dim3(576), 256, 0, stream>>>(Opart, Lpart, out);
}

// Round 15
// 138.782 us; speedup vs baseline: 1.0244x; 1.0138x over previous
//
#include <hip/hip_runtime.h>
#include <hip/hip_bf16.h>

#define T_TOT 2304
#define DDIM  1024
#define NH    16
#define DK    64
#define SLEN  128
#define SEQ   2048

typedef __bf16 bf16x8 __attribute__((ext_vector_type(8)));
typedef __bf16 bf16x4 __attribute__((ext_vector_type(4)));
typedef float  f32x4  __attribute__((ext_vector_type(4)));

__device__ __forceinline__ void async_copy16(const void* gsrc, void* ldst) {
  __builtin_amdgcn_global_load_lds(
      (const __attribute__((address_space(1))) void*)gsrc,
      (__attribute__((address_space(3))) void*)ldst, 16, 0, 0);
}

// ---------------- convert: x -> bf16 (vectorized); W[h][d][n] -> Wt[m][h][n][d] via LDS transpose
__global__ __launch_bounds__(256) void convert_kernel(
    const float* __restrict__ x,
    const float* __restrict__ Wq, const float* __restrict__ Wk,
    const float* __restrict__ Wv, const float* __restrict__ Wqs,
    const float* __restrict__ Wks, const float* __restrict__ Wvs,
    __bf16* __restrict__ xb, __bf16* __restrict__ Wt) {
  const int b = blockIdx.x;
  const int tid = threadIdx.x;
  if (b < 576) {
    const float4* xin = (const float4*)x;
#pragma unroll
    for (int it = 0; it < 4; ++it) {
      int idx4 = b * 1024 + it * 256 + tid;
      float4 v = xin[idx4];
      bf16x4 o;
      o[0] = (__bf16)v.x; o[1] = (__bf16)v.y; o[2] = (__bf16)v.z; o[3] = (__bf16)v.w;
      *(bf16x4*)(xb + (size_t)idx4 * 4) = o;
    }
    return;
  }
  __shared__ float tile[64 * 65];
  const int wb = b - 576;
  const int m  = wb >> 8;
  const int rem = wb & 255;
  const int h  = rem >> 4;
  const int dt = rem & 15;
  const int d0 = dt * 64;
  const float* Wsrc = (m == 0 ? Wq : m == 1 ? Wk : m == 2 ? Wv
                      : m == 3 ? Wqs : m == 4 ? Wks : Wvs) + (size_t)h * (DDIM * DK);
#pragma unroll
  for (int rr = 0; rr < 4; ++rr) {
    int drow = rr * 16 + (tid >> 4);
    int nc   = (tid & 15) * 4;
    float4 v = *(const float4*)(Wsrc + (size_t)(d0 + drow) * DK + nc);
    tile[(nc + 0) * 65 + drow] = v.x;
    tile[(nc + 1) * 65 + drow] = v.y;
    tile[(nc + 2) * 65 + drow] = v.z;
    tile[(nc + 3) * 65 + drow] = v.w;
  }
  __syncthreads();
  {
    int n  = tid >> 2;
    int rg = (tid & 3) * 16;
    __bf16* dst = Wt + (((size_t)(m * NH + h)) * DK + n) * DDIM + d0 + rg;
    bf16x8 o0, o1;
#pragma unroll
    for (int e = 0; e < 8; e++) o0[e] = (__bf16)tile[n * 65 + rg + e];
#pragma unroll
    for (int e = 0; e < 8; e++) o1[e] = (__bf16)tile[n * 65 + rg + 8 + e];
    *(bf16x8*)dst = o0;
    *(bf16x8*)(dst + 8) = o1;
  }
}

// ---------------- proj v3 (measured-best ~26us): 64x128 tiles, grid (8,36,3)=864 blocks.
__global__ __launch_bounds__(256) void proj_kernel(
    const __bf16* __restrict__ xb, const __bf16* __restrict__ Wt,
    const float* __restrict__ scal,
    __bf16* __restrict__ qkv, __bf16* __restrict__ vt) {
  const int ntile = blockIdx.x;   // 0..7
  const int rt    = blockIdx.y;   // 0..35 (64-row tiles)
  const int which = blockIdx.z;   // 0=q 1=k 2=v
  const int r0    = rt * 64;
  const int m     = (rt < 2 || rt >= 34) ? which + 3 : which;

  __shared__ __bf16 Xs[64 * 64];     // 8 KB
  __shared__ __bf16 Wsh[128 * 64];   // 16 KB

  const int tid  = threadIdx.x;
  const int wave = tid >> 6, lane = tid & 63;
  const int quad = lane >> 4, lc = lane & 15;
  const int wr   = wave >> 1, wc = wave & 1;
  const int h    = ntile * 2 + wc;

  const __bf16* Wbase = Wt + ((size_t)m * NH) * (DK * DDIM) + (size_t)(ntile * 128) * DDIM;

  const f32x4 fz = {0.f, 0.f, 0.f, 0.f};
  f32x4 acc[2][4];
#pragma unroll
  for (int i = 0; i < 2; i++)
#pragma unroll
    for (int j = 0; j < 4; j++) acc[i][j] = fz;

  for (int k0 = 0; k0 < DDIM; k0 += 64) {
#pragma unroll
    for (int it = 0; it < 2; ++it) {
      int L = it * 256 + tid;
      int row = L >> 3, c = (L & 7) ^ (row & 7);
      async_copy16(xb + (size_t)(r0 + row) * DDIM + k0 + c * 8,
                   (char*)Xs + (size_t)(it * 256 + wave * 64) * 16);
    }
#pragma unroll
    for (int it = 0; it < 4; ++it) {
      int L = it * 256 + tid;
      int row = L >> 3, c = (L & 7) ^ (row & 7);
      async_copy16(Wbase + (size_t)row * DDIM + k0 + c * 8,
                   (char*)Wsh + (size_t)(it * 256 + wave * 64) * 16);
    }
    __syncthreads();
#pragma unroll
    for (int kk = 0; kk < 2; kk++) {
      bf16x8 afr[2], bfr[4];
#pragma unroll
      for (int i = 0; i < 2; i++) {
        int row = wr * 32 + i * 16 + lc;
        int ch  = (kk * 4 + quad) ^ (row & 7);
        afr[i] = *(const bf16x8*)(Xs + (row * 8 + ch) * 8);
      }
#pragma unroll
      for (int j = 0; j < 4; j++) {
        int row = wc * 64 + j * 16 + lc;
        int ch  = (kk * 4 + quad) ^ (row & 7);
        bfr[j] = *(const bf16x8*)(Wsh + (row * 8 + ch) * 8);
      }
#pragma unroll
      for (int i = 0; i < 2; i++)
#pragma unroll
        for (int j = 0; j < 4; j++)
          acc[i][j] = __builtin_amdgcn_mfma_f32_16x16x32_bf16(afr[i], bfr[j], acc[i][j], 0, 0, 0);
    }
    __syncthreads();
  }

  const float qscale = (which == 0) ? scal[h] * 1.44269504088896f : 1.0f;
  float inv4[2][4];
#pragma unroll
  for (int i = 0; i < 2; i++) {
#pragma unroll
    for (int r = 0; r < 4; r++) {
      float s = 0.f;
#pragma unroll
      for (int j = 0; j < 4; j++) { float v = acc[i][j][r]; s += v * v; }
#pragma unroll
      for (int off = 1; off < 16; off <<= 1) s += __shfl_xor(s, off, 64);
      inv4[i][r] = qscale / fmaxf(sqrtf(s), 1e-12f);
    }
  }
  if (which == 2) {
    __bf16* vtp = vt + (size_t)h * (DK * T_TOT);
#pragma unroll
    for (int i = 0; i < 2; i++) {
      int rowbase = r0 + wr * 32 + i * 16 + quad * 4;
#pragma unroll
      for (int j = 0; j < 4; j++) {
        bf16x4 o;
#pragma unroll
        for (int r = 0; r < 4; r++) o[r] = (__bf16)(acc[i][j][r] * inv4[i][r]);
        *(bf16x4*)(vtp + (size_t)(j * 16 + lc) * T_TOT + rowbase) = o;
      }
    }
  } else {
    __bf16* outp = qkv + ((size_t)(which * NH + h)) * ((size_t)T_TOT * DK);
#pragma unroll
    for (int i = 0; i < 2; i++)
#pragma unroll
      for (int r = 0; r < 4; r++) {
        int row = r0 + wr * 32 + i * 16 + quad * 4 + r;
#pragma unroll
        for (int j = 0; j < 4; j++)
          outp[(size_t)row * DK + j * 16 + lc] = (__bf16)(acc[i][j][r] * inv4[i][r]);
      }
  }
}

// ---------------- flash attention v19: r14 structure EXACTLY; softmax exp2 uses raw
// v_exp_f32 (input range |s| <= 0.19: no denormal/range fixup needed).
__global__ __launch_bounds__(256, 3) void attn_kernel(
    const __bf16* __restrict__ qkv, const __bf16* __restrict__ vt,
    __bf16* __restrict__ Opart, float* __restrict__ Lpart) {
  const int b    = blockIdx.x;          // 0..1151
  const int h    = b & 15;
  const int rest = b >> 4;              // 0..71
  const int qg   = 35 - (rest >> 1);    // big work first
  const int si   = rest & 1;            // kv split index
  const int q0b  = qg * 64;
  const int tid  = threadIdx.x;
  const int wave = tid >> 6, lane = tid & 63;
  const int quad = lane >> 4, lc = lane & 15;

  const __bf16* qp = qkv + ((size_t)h) * ((size_t)T_TOT * DK);
  const __bf16* kp = qkv + ((size_t)(NH + h)) * ((size_t)T_TOT * DK);
  const __bf16* vp = vt + (size_t)h * (DK * T_TOT);

  // 40 KB shared: Ks[2][64*64] | Vs[2][64*64] | P[4 waves][16*64]
  __shared__ __align__(16) char smem[40960];
  __bf16* Ks = (__bf16*)smem;
  __bf16* Vs = (__bf16*)(smem + 16384);
  __bf16* Pw = (__bf16*)(smem + 32768) + wave * 1024;  // own [16 q][64 kv] slice

  // Q B-frags for this wave's 16 q rows: B[k=d][n=q=lc]
  bf16x8 qf[2];
#pragma unroll
  for (int kk = 0; kk < 2; kk++)
    qf[kk] = *(const bf16x8*)(qp + (size_t)(q0b + wave * 16 + lc) * DK + kk * 32 + quad * 8);

  const f32x4 fz = {0.f, 0.f, 0.f, 0.f};
  f32x4 acc[4];                          // O^T: d-tile dt -> rows quad*4+r, col q=lc
#pragma unroll
  for (int dt = 0; dt < 4; dt++) acc[dt] = fz;
  float lp = 0.f;

  // kv range for this split
  const int jsAll = (q0b >= SLEN + SEQ) ? 2 : 0;
  const int n     = qg - jsAll + 1;
  const int half  = (n + 1) >> 1;
  const int j0    = jsAll + (si ? half : 0);
  const int j1    = si ? qg : (jsAll + half - 1);

  auto stage = [&](int j, int bufi) {
    const __bf16* kT = kp + (size_t)j * 64 * DK;
    __bf16* Kd = Ks + bufi * 4096;
    __bf16* Vd = Vs + bufi * 4096;
#pragma unroll
    for (int it = 0; it < 2; ++it) {
      int L = it * 256 + tid;
      int row = L >> 3, c = (L & 7) ^ (row & 7);
      async_copy16(kT + (size_t)row * DK + c * 8,
                   (char*)Kd + (size_t)(it * 256 + wave * 64) * 16);
    }
#pragma unroll
    for (int it = 0; it < 2; ++it) {
      int L = it * 256 + tid;
      int d = L >> 3, c = (L & 7) ^ (d & 7);
      async_copy16(vp + (size_t)d * T_TOT + j * 64 + c * 8,
                   (char*)Vd + (size_t)(it * 256 + wave * 64) * 16);
    }
  };

  int cur = 0;
  if (j0 <= j1) stage(j0, 0);

  for (int j = j0; j <= j1; ++j) {
    __syncthreads();                    // tile j staged; buffers safe to swap
    if (j < j1) stage(j + 1, cur ^ 1);

    const __bf16* Kc = Ks + cur * 4096;
    const __bf16* Vc = Vs + cur * 4096;

    // S^T[64 kv][16 q]: A = K-frag (m=kv), B = qf (n=q)
    f32x4 s[4];
    __builtin_amdgcn_s_setprio(1);
#pragma unroll
    for (int kvt = 0; kvt < 4; kvt++) {
      int row = kvt * 16 + lc;
      bf16x8 a0 = *(const bf16x8*)(Kc + (row * 8 + (quad ^ (lc & 7))) * 8);
      bf16x8 a1 = *(const bf16x8*)(Kc + (row * 8 + ((4 + quad) ^ (lc & 7))) * 8);
      f32x4 t = __builtin_amdgcn_mfma_f32_16x16x32_bf16(a0, qf[0], fz, 0, 0, 0);
      s[kvt]  = __builtin_amdgcn_mfma_f32_16x16x32_bf16(a1, qf[1], t, 0, 0, 0);
    }
    __builtin_amdgcn_s_setprio(0);

    const bool diag = (j == qg);
    // fixed-shift softmax (raw v_exp_f32) + pack into wave-private swizzled P slice
#pragma unroll
    for (int kvt = 0; kvt < 4; kvt++) {
      if (diag) {
#pragma unroll
        for (int r = 0; r < 4; r++)
          if ((kvt * 16 + quad * 4 + r) > (wave * 16 + lc)) s[kvt][r] = -__builtin_inff();
      }
      bf16x4 pb;
#pragma unroll
      for (int r = 0; r < 4; r++) {
        float pe = __builtin_amdgcn_exp2f(s[kvt][r]);
        lp += pe;
        pb[r] = (__bf16)pe;
      }
      int c = (kvt * 4 + quad) ^ ((lc & 7) << 1);   // 8B-chunk XOR swizzle
      *(bf16x4*)(Pw + lc * 64 + c * 4) = pb;
    }

    // PV: O^T[64d][16q] += V^T P^T  (wave-private P, in-order LDS: no barrier)
    bf16x8 pB[2];
#pragma unroll
    for (int kk = 0; kk < 2; kk++)
      pB[kk] = *(const bf16x8*)(Pw + lc * 64 + ((kk * 8 + quad * 2) ^ ((lc & 7) << 1)) * 4);
    __builtin_amdgcn_s_setprio(1);
#pragma unroll
    for (int dt = 0; dt < 4; dt++) {
      int row = dt * 16 + lc;
#pragma unroll
      for (int kk = 0; kk < 2; kk++) {
        bf16x8 vA = *(const bf16x8*)(Vc + (row * 8 + ((kk * 4 + quad) ^ (lc & 7))) * 8);
        acc[dt] = __builtin_amdgcn_mfma_f32_16x16x32_bf16(vA, pB[kk], acc[dt], 0, 0, 0);
      }
    }
    __builtin_amdgcn_s_setprio(0);
    cur ^= 1;
  }

  // l reduce: quads hold disjoint kv partials for q=lc
  lp += __shfl_xor(lp, 16, 64);
  lp += __shfl_xor(lp, 32, 64);
  if (lane < 16) Lpart[(size_t)b * 64 + wave * 16 + lane] = lp;

  // O^T[d][q] -> Opart[q][d] (bf16) via per-wave LDS transpose (reuse smem; pad 68)
  __syncthreads();
  float* Ot = (float*)smem + wave * (16 * 68);
#pragma unroll
  for (int dt = 0; dt < 4; dt++)
#pragma unroll
    for (int r = 0; r < 4; r++)
      Ot[lc * 68 + dt * 16 + quad * 4 + r] = acc[dt][r];

  __bf16* Ob = Opart + (size_t)b * 4096;
  const int q2 = lane >> 2, dsg = (lane & 3) * 16;
#pragma unroll
  for (int g = 0; g < 4; g++) {
    f32x4 v = *(const f32x4*)(&Ot[q2 * 68 + dsg + g * 4]);
    bf16x4 o;
#pragma unroll
    for (int r = 0; r < 4; r++) o[r] = (__bf16)v[r];
    *(bf16x4*)(&Ob[(size_t)(wave * 16 + q2) * 64 + dsg + g * 4]) = o;
  }
}

// ---------------- combine: out = (O0 + O1) / (l0 + l1), bf16 partials, bf16x8 loads
__global__ __launch_bounds__(256) void combine_kernel(
    const __bf16* __restrict__ Opart, const float* __restrict__ Lpart,
    float* __restrict__ out) {
  const int b  = blockIdx.x;            // 0..575
  const int h  = b & 15;
  const int qg = b >> 4;
  const int b0 = (((35 - qg) * 2) << 4) | h;
  const int b1 = b0 + 16;
  const int tid = threadIdx.x;

  __shared__ float invl[64];
  if (tid < 64)
    invl[tid] = 1.0f / (Lpart[(size_t)b0 * 64 + tid] + Lpart[(size_t)b1 * 64 + tid]);
  __syncthreads();

  const __bf16* O0 = Opart + (size_t)b0 * 4096;
  const __bf16* O1 = Opart + (size_t)b1 * 4096;
  float* op = out + ((size_t)h * T_TOT + qg * 64) * DK;
#pragma unroll
  for (int it = 0; it < 2; ++it) {
    int i8 = it * 256 + tid;            // bf16x8 index, 0..511 (8 | 64 -> no row cross)
    bf16x8 a = *(const bf16x8*)(&O0[(size_t)i8 * 8]);
    bf16x8 c = *(const bf16x8*)(&O1[(size_t)i8 * 8]);
    float iv = invl[i8 >> 3];
    f32x4 o0, o1;
#pragma unroll
    for (int r = 0; r < 4; r++) {
      o0[r] = ((float)a[r]     + (float)c[r])     * iv;
      o1[r] = ((float)a[r + 4] + (float)c[r + 4]) * iv;
    }
    *(f32x4*)(&op[(size_t)i8 * 8])     = o0;
    *(f32x4*)(&op[(size_t)i8 * 8 + 4]) = o1;
  }
}

extern "C" void kernel_launch(void* const* d_in, const int* in_sizes, int n_in,
                              void* d_out, int out_size, void* d_ws, size_t ws_size,
                              hipStream_t stream) {
  const float* x    = (const float*)d_in[0];
  const float* Wq   = (const float*)d_in[1];
  const float* Wk   = (const float*)d_in[2];
  const float* Wv   = (const float*)d_in[3];
  const float* Wqs  = (const float*)d_in[4];
  const float* Wks  = (const float*)d_in[5];
  const float* Wvs  = (const float*)d_in[6];
  const float* scal = (const float*)d_in[7];
  float* out = (float*)d_out;

  char* ws = (char*)d_ws;
  size_t off = 0;
  __bf16* xb    = (__bf16*)(ws + off); off += (size_t)T_TOT * DDIM * 2;
  __bf16* Wt    = (__bf16*)(ws + off); off += (size_t)6 * NH * DK * DDIM * 2;
  __bf16* qkv   = (__bf16*)(ws + off); off += (size_t)2 * NH * T_TOT * DK * 2;
  __bf16* vt    = (__bf16*)(ws + off); off += (size_t)NH * DK * T_TOT * 2;
  __bf16* Opart = (__bf16*)(ws + off); off += (size_t)1152 * 4096 * 2;
  float*  Lpart = (float*)(ws + off);

  convert_kernel<<<2112, 256, 0, stream>>>(x, Wq, Wk, Wv, Wqs, Wks, Wvs, xb, Wt);
  proj_kernel<<<dim3(8, 36, 3), 256, 0, stream>>>(xb, Wt, scal, qkv, vt);
  attn_kernel<<<dim3(1152), 256, 0, stream>>>(qkv, vt, Opart, Lpart);
  combine_kernel<<<dim3(576), 256, 0, stream>>>(Opart, Lpart, out);
}